// Round 1
// baseline (847.780 us; speedup 1.0000x reference)
//
#include <hip/hip_runtime.h>

#define B_    8
#define C_    64
#define H_    128
#define W_    128
#define K_    9
#define J_    18     // 2*K
#define COUT_ 64
#define TPX   16     // pixels per block (row segment)
#define CK    576    // C_*K_

// round-to-nearest-even fp32 -> bf16
__device__ __forceinline__ unsigned short f2bf(float f) {
    unsigned int u = __float_as_uint(f);
    u = u + 0x7fffu + ((u >> 16) & 1u);
    return (unsigned short)(u >> 16);
}

// conv tap (r*3+s) -> 4x4 patch index (r*4+s)
constexpr int PMAP[9] = {0, 1, 2, 4, 5, 6, 8, 9, 10};

__global__ __launch_bounds__(256, 2)
void dcn_fused(const float* __restrict__ x,
               const float* __restrict__ ow,
               const float* __restrict__ ob,
               const float* __restrict__ dw,
               const float* __restrict__ db,
               float* __restrict__ out) {
    // offset weights as packed bf16 pairs: [c][pair t<81] covering elems c*162+2t,+1
    __shared__ unsigned int ow_s[C_ * 81];                 // 20736 B
    // sampled values: [px][c*9+k], row stride 576 floats (16B-aligned rows)
    __shared__ __align__(16) float sbuf[TPX * CK];         // 36864 B  (total 57.6 KB -> 2 blk/CU)

    const int tid  = threadIdx.x;
    const int wave = tid >> 6;
    const int lane = tid & 63;

    const int bid = blockIdx.x;
    const int b   = bid >> 10;            // / (128 * 8)
    const int rem = bid & 1023;
    const int h   = rem >> 3;
    const int w0  = (rem & 7) << 4;       // tile of 16 consecutive w

    // ---- stage offset-conv weights (bf16-packed) ----
    const float2* ow2 = (const float2*)ow;
    for (int i = tid; i < C_ * 81; i += 256) {
        float2 f = ow2[i];                // elems 2i, 2i+1  ==  c*162 + 2t, +1
        ow_s[i] = (unsigned int)f2bf(f.x) | ((unsigned int)f2bf(f.y) << 16);
    }

    // per-lane (=channel) conv bias
    float ob_r[J_];
    #pragma unroll
    for (int j = 0; j < J_; j++) ob_r[j] = ob[lane * J_ + j];

    __syncthreads();

    const float* xc = x + (size_t)(b * C_ + lane) * (H_ * W_);
    const unsigned int* owc = ow_s + lane * 81;

    // ---- phase A: conv + softmax + bilinear sample, 4 px per wave ----
    for (int i = 0; i < 4; i++) {
        const int px = (wave << 2) + i;
        const int wp = w0 + px;

        // 4x4 zero-padded patch (covers conv 3x3 AND all bilinear corners)
        float P[16];
        #pragma unroll
        for (int r = 0; r < 4; r++) {
            const int y = h - 1 + r;
            const bool yv = (unsigned)y < (unsigned)H_;
            #pragma unroll
            for (int s = 0; s < 4; s++) {
                const int xx = wp - 1 + s;
                const bool ok = yv && ((unsigned)xx < (unsigned)W_);
                P[r * 4 + s] = ok ? xc[y * W_ + xx] : 0.0f;
            }
        }

        // depthwise 3x3 conv -> 18 outputs for this channel
        float v[J_];
        #pragma unroll
        for (int j = 0; j < J_; j++) v[j] = ob_r[j];
        #pragma unroll
        for (int t = 0; t < 81; t++) {
            const unsigned int pw = owc[t];
            const float wlo = __uint_as_float(pw << 16);
            const float whi = __uint_as_float(pw & 0xffff0000u);
            v[(2 * t) / 9]     = fmaf(wlo, P[PMAP[(2 * t) % 9]],     v[(2 * t) / 9]);
            v[(2 * t + 1) / 9] = fmaf(whi, P[PMAP[(2 * t + 1) % 9]], v[(2 * t + 1) / 9]);
        }

        // softmax over 1152 = 64 lanes x 18
        float m = v[0];
        #pragma unroll
        for (int j = 1; j < J_; j++) m = fmaxf(m, v[j]);
        #pragma unroll
        for (int off = 32; off >= 1; off >>= 1) m = fmaxf(m, __shfl_xor(m, off, 64));
        float sum = 0.0f;
        #pragma unroll
        for (int j = 0; j < J_; j++) { v[j] = __expf(v[j] - m); sum += v[j]; }
        #pragma unroll
        for (int off = 32; off >= 1; off >>= 1) sum += __shfl_xor(sum, off, 64);
        const float inv = 1.0f / sum;

        // bilinear: dy,dx in (0,1) => floor(py)=h-1+ky statically; corners are patch entries
        #pragma unroll
        for (int k = 0; k < K_; k++) {
            const float dy = v[2 * k] * inv;
            const float dx = v[2 * k + 1] * inv;
            const int ky = k / 3, kx = k % 3;
            const float a  = P[ky * 4 + kx],     bb = P[ky * 4 + kx + 1];
            const float c  = P[ky * 4 + kx + 4], dd = P[ky * 4 + kx + 5];
            const float top = a + dx * (bb - a);
            const float bot = c + dx * (dd - c);
            sbuf[px * CK + lane * K_ + k] = top + dy * (bot - top);
        }
    }

    __syncthreads();

    // ---- phase B: einsum  out[o,px] = sum_ck sbuf[px][ck] * dw[o][ck] ----
    const int o = lane;
    const int p0 = wave << 2;
    float a0 = 0.f, a1 = 0.f, a2 = 0.f, a3 = 0.f;
    const float4* dw4 = (const float4*)(dw + o * CK);
    const float4* s0r = (const float4*)(sbuf + (p0 + 0) * CK);
    const float4* s1r = (const float4*)(sbuf + (p0 + 1) * CK);
    const float4* s2r = (const float4*)(sbuf + (p0 + 2) * CK);
    const float4* s3r = (const float4*)(sbuf + (p0 + 3) * CK);
    for (int cq = 0; cq < CK / 4; cq++) {
        const float4 wv = dw4[cq];
        const float4 s0 = s0r[cq];
        const float4 s1 = s1r[cq];
        const float4 s2 = s2r[cq];
        const float4 s3 = s3r[cq];
        a0 = fmaf(s0.x, wv.x, a0); a0 = fmaf(s0.y, wv.y, a0); a0 = fmaf(s0.z, wv.z, a0); a0 = fmaf(s0.w, wv.w, a0);
        a1 = fmaf(s1.x, wv.x, a1); a1 = fmaf(s1.y, wv.y, a1); a1 = fmaf(s1.z, wv.z, a1); a1 = fmaf(s1.w, wv.w, a1);
        a2 = fmaf(s2.x, wv.x, a2); a2 = fmaf(s2.y, wv.y, a2); a2 = fmaf(s2.z, wv.z, a2); a2 = fmaf(s2.w, wv.w, a2);
        a3 = fmaf(s3.x, wv.x, a3); a3 = fmaf(s3.y, wv.y, a3); a3 = fmaf(s3.z, wv.z, a3); a3 = fmaf(s3.w, wv.w, a3);
    }
    const float bias = db[o];
    float4 res;
    res.x = a0 + bias; res.y = a1 + bias; res.z = a2 + bias; res.w = a3 + bias;
    float* op = out + (size_t)((b * COUT_ + o) * H_ + h) * W_ + w0 + p0;
    *(float4*)op = res;
}

extern "C" void kernel_launch(void* const* d_in, const int* in_sizes, int n_in,
                              void* d_out, int out_size, void* d_ws, size_t ws_size,
                              hipStream_t stream) {
    (void)in_sizes; (void)n_in; (void)out_size; (void)d_ws; (void)ws_size;
    const float* x  = (const float*)d_in[0];
    const float* ow = (const float*)d_in[1];
    const float* ob = (const float*)d_in[2];
    const float* dw = (const float*)d_in[3];
    const float* db = (const float*)d_in[4];
    dcn_fused<<<dim3(B_ * H_ * (W_ / TPX)), dim3(256), 0, stream>>>(
        x, ow, ob, dw, db, (float*)d_out);
}

// Round 2
// 554.535 us; speedup vs baseline: 1.5288x; 1.5288x over previous
//
#include <hip/hip_runtime.h>

#define B_    8
#define C_    64
#define H_    128
#define W_    128
#define K_    9
#define J_    18     // 2*K
#define COUT_ 64
#define TPX   16     // pixels per block
#define CK    576    // C_*K_
#define SROW  584    // sbuf row stride (bf16 elems); 584*2=1168B = 73*16 (16B-aligned), 292 dwords ≡ 4 mod 32 banks

typedef __attribute__((ext_vector_type(8))) short short8;
typedef __attribute__((ext_vector_type(4))) float float4v;

// round-to-nearest-even fp32 -> bf16
__device__ __forceinline__ unsigned short f2bf(float f) {
    unsigned int u = __float_as_uint(f);
    u = u + 0x7fffu + ((u >> 16) & 1u);
    return (unsigned short)(u >> 16);
}

// conv tap (r*3+s) -> strip index r*7+s  (strip is 4 rows x 7 cols)
#define TMAP0 0
#define TMAP1 1
#define TMAP2 2
#define TMAP3 7
#define TMAP4 8
#define TMAP5 9
#define TMAP6 14
#define TMAP7 15
#define TMAP8 16
__device__ __constant__ int TMAP[9] = {0, 1, 2, 7, 8, 9, 14, 15, 16};

// -------- pre-kernel: NCHW -> NHWC transpose of x into workspace --------
__global__ __launch_bounds__(256)
void nchw_to_nhwc(const float* __restrict__ x, float* __restrict__ xt) {
    __shared__ float tile[64][65];
    const int bid = blockIdx.x;          // b*256 + h*2 + wt
    const int wt  = bid & 1;
    const int h   = (bid >> 1) & 127;
    const int b   = bid >> 8;
    const int w0  = wt << 6;
    const int q   = threadIdx.x >> 6;
    const int l   = threadIdx.x & 63;
    #pragma unroll
    for (int r = 0; r < 16; r++) {
        const int c = q * 16 + r;
        tile[c][l] = x[((size_t)(b * C_ + c) * H_ + h) * W_ + w0 + l];
    }
    __syncthreads();
    #pragma unroll
    for (int r = 0; r < 16; r++) {
        const int w = q * 16 + r;
        xt[((size_t)(b * H_ + h) * W_ + w0 + w) * C_ + l] = tile[l][w];
    }
}

// -------- fused kernel --------
template<bool NHWC>
__global__ __launch_bounds__(256, 4)
void dcn_fused(const float* __restrict__ xsrc,
               const float* __restrict__ ow,
               const float* __restrict__ ob,
               const float* __restrict__ dw,
               const float* __restrict__ db,
               float* __restrict__ out) {
    // offset weights, packed bf16 pairs: [c][pair t<81] covering elems c*162+2t, +1
    __shared__ unsigned int ow_s[C_ * 81];                       // 20736 B
    // sampled values, bf16: [px 0..15][c*9+k], row stride SROW
    __shared__ __align__(16) unsigned short sbuf[TPX * SROW];    // 18688 B  -> total 39424 B, 4 blk/CU

    const int tid  = threadIdx.x;
    const int wave = tid >> 6;
    const int lane = tid & 63;

    const int bid = blockIdx.x;
    const int b   = bid >> 10;
    const int rem = bid & 1023;
    const int h   = rem >> 3;
    const int w0  = (rem & 7) << 4;

    // stage bf16-packed offset weights
    const float2* ow2 = (const float2*)ow;
    for (int i = tid; i < C_ * 81; i += 256) {
        float2 f = ow2[i];
        ow_s[i] = (unsigned int)f2bf(f.x) | ((unsigned int)f2bf(f.y) << 16);
    }

    float ob_r[J_];
    #pragma unroll
    for (int j = 0; j < J_; j++) ob_r[j] = ob[lane * J_ + j];

    __syncthreads();

    // ---- phase A: conv + softmax + bilinear, 4 px per wave ----
    const int wbase = w0 + (wave << 2);
    const unsigned int* owc = ow_s + lane * 81;

    // 4x19 region needed is per-pixel 4x4; wave strip = 4 rows x 7 cols (wbase-1 .. wbase+5)
    float S[28];
    #pragma unroll
    for (int r = 0; r < 4; r++) {
        const int y = h - 1 + r;
        const bool yv = (unsigned)y < (unsigned)H_;
        #pragma unroll
        for (int s = 0; s < 7; s++) {
            const int xx = wbase - 1 + s;
            const bool ok = yv && ((unsigned)xx < (unsigned)W_);
            float val;
            if (NHWC) {
                const float* p = xsrc + ((size_t)(b * H_ + (y & 127)) * W_ + (xx & 127)) * C_ + lane;
                val = ok ? *p : 0.0f;       // coalesced: lane = c contiguous
            } else {
                const float* p = xsrc + ((size_t)(b * C_ + lane) * H_ + (y & 127)) * W_ + (xx & 127);
                val = ok ? *p : 0.0f;
            }
            S[r * 7 + s] = val;
        }
    }

    #pragma unroll
    for (int i = 0; i < 4; i++) {
        const int px = (wave << 2) + i;

        // depthwise 3x3 conv -> 18 outputs for this channel (lane = c)
        float v[J_];
        #pragma unroll
        for (int j = 0; j < J_; j++) v[j] = ob_r[j];
        #pragma unroll
        for (int t = 0; t < 81; t++) {
            const unsigned int pw = owc[t];
            const float wlo = __uint_as_float(pw << 16);
            const float whi = __uint_as_float(pw & 0xffff0000u);
            const int e0 = 2 * t, e1 = 2 * t + 1;
            v[e0 / 9] = fmaf(wlo, S[TMAP[e0 % 9] + i], v[e0 / 9]);
            v[e1 / 9] = fmaf(whi, S[TMAP[e1 % 9] + i], v[e1 / 9]);
        }

        // softmax over 1152 = 64 lanes x 18
        float m = v[0];
        #pragma unroll
        for (int j = 1; j < J_; j++) m = fmaxf(m, v[j]);
        #pragma unroll
        for (int off = 32; off >= 1; off >>= 1) m = fmaxf(m, __shfl_xor(m, off, 64));
        float sum = 0.0f;
        #pragma unroll
        for (int j = 0; j < J_; j++) { v[j] = __expf(v[j] - m); sum += v[j]; }
        #pragma unroll
        for (int off = 32; off >= 1; off >>= 1) sum += __shfl_xor(sum, off, 64);
        const float inv = 1.0f / sum;

        // bilinear: dy,dx in (0,1) -> corners are strip entries
        #pragma unroll
        for (int k = 0; k < K_; k++) {
            const float dy = v[2 * k] * inv;
            const float dx = v[2 * k + 1] * inv;
            const int base = TMAP[k] + i;          // ky*7 + kx + i
            const float a  = S[base],     bb = S[base + 1];
            const float c  = S[base + 7], dd = S[base + 8];
            const float top = a + dx * (bb - a);
            const float bot = c + dx * (dd - c);
            sbuf[px * SROW + lane * K_ + k] = f2bf(top + dy * (bot - top));
        }
    }

    __syncthreads();

    // ---- phase B: MFMA einsum. Per wave: 16 px x 16 outs, K=576 ----
    const int quad = lane >> 4;
    const int o    = (wave << 4) + (lane & 15);
    float4v acc = {0.f, 0.f, 0.f, 0.f};
    const unsigned short* arow = sbuf + (lane & 15) * SROW + quad * 8;  // A[m=lane&15][k=quad*8+j]
    const float* brow = dw + (size_t)o * CK + quad * 8;                 // B[k][n=o], k contiguous
    #pragma unroll
    for (int t = 0; t < 18; t++) {
        short8 afrag = *(const short8*)(arow + t * 32);
        float4 b0 = *(const float4*)(brow + t * 32);
        float4 b1 = *(const float4*)(brow + t * 32 + 4);
        union { short8 s8; unsigned short u[8]; } bf;
        bf.u[0] = f2bf(b0.x); bf.u[1] = f2bf(b0.y); bf.u[2] = f2bf(b0.z); bf.u[3] = f2bf(b0.w);
        bf.u[4] = f2bf(b1.x); bf.u[5] = f2bf(b1.y); bf.u[6] = f2bf(b1.z); bf.u[7] = f2bf(b1.w);
        acc = __builtin_amdgcn_mfma_f32_16x16x32_bf16(afrag, bf.s8, acc, 0, 0, 0);
    }
    const float bias = db[o];
    const int px0 = quad << 2;                    // row = quad*4 + reg -> consecutive w
    float4 res;
    res.x = acc[0] + bias; res.y = acc[1] + bias; res.z = acc[2] + bias; res.w = acc[3] + bias;
    *(float4*)(out + ((size_t)(b * COUT_ + o) * H_ + h) * W_ + w0 + px0) = res;
}

extern "C" void kernel_launch(void* const* d_in, const int* in_sizes, int n_in,
                              void* d_out, int out_size, void* d_ws, size_t ws_size,
                              hipStream_t stream) {
    (void)in_sizes; (void)n_in; (void)out_size;
    const float* x  = (const float*)d_in[0];
    const float* ow = (const float*)d_in[1];
    const float* ob = (const float*)d_in[2];
    const float* dw = (const float*)d_in[3];
    const float* db = (const float*)d_in[4];
    float* outp = (float*)d_out;

    const size_t xbytes = (size_t)B_ * C_ * H_ * W_ * sizeof(float);
    if (ws_size >= xbytes) {
        float* xt = (float*)d_ws;
        nchw_to_nhwc<<<dim3(B_ * H_ * (W_ / 64)), dim3(256), 0, stream>>>(x, xt);
        dcn_fused<true><<<dim3(B_ * H_ * (W_ / TPX)), dim3(256), 0, stream>>>(
            xt, ow, ob, dw, db, outp);
    } else {
        dcn_fused<false><<<dim3(B_ * H_ * (W_ / TPX)), dim3(256), 0, stream>>>(
            x, ow, ob, dw, db, outp);
    }
}